// Round 7
// baseline (249.437 us; speedup 1.0000x reference)
//
#include <hip/hip_runtime.h>
#include <hip/hip_bf16.h>

typedef __bf16 bf16x8 __attribute__((ext_vector_type(8)));
typedef __bf16 bf16x4 __attribute__((ext_vector_type(4)));
typedef float f32x4 __attribute__((ext_vector_type(4)));
typedef unsigned int u32;
typedef __attribute__((address_space(3))) u32 lds_u32_t;
typedef __attribute__((address_space(1))) u32 glb_u32_t;

#define MROWS 8192      // B*S
#define NEXP 4352       // 2*QK + 2*EXPAND
#define DDIM 1024
#define EDIM 2048

// Raw sync primitives: NO "memory" clobber anywhere in the hot loop.
// "memory"-clobbered asm makes the waitcnt pass pre-drain all counters
// (drain-0 regime, the r3-r6 plateau). Ordering is pinned with
// sched_barrier(0) instead.
#define S_VM0_BARE() asm volatile("s_waitcnt vmcnt(0)")
#define SCHED_PIN() __builtin_amdgcn_sched_barrier(0)

__device__ __forceinline__ void async16(const void* g, void* l) {
  __builtin_amdgcn_global_load_lds((const glb_u32_t*)g, (lds_u32_t*)l, 16, 0, 0);
}

// ---------------- LayerNorm + bf16 cast ----------------
__global__ __launch_bounds__(256) void ln_kernel(const float* __restrict__ x,
                                                 const float* __restrict__ wgt,
                                                 __bf16* __restrict__ xn) {
  const int row = blockIdx.x;
  const int t = threadIdx.x;
  const float4 v = ((const float4*)(x + (size_t)row * DDIM))[t];
  float s = v.x + v.y + v.z + v.w;
  float ss = v.x * v.x + v.y * v.y + v.z * v.z + v.w * v.w;
  #pragma unroll
  for (int o = 32; o > 0; o >>= 1) {
    s += __shfl_down(s, o);
    ss += __shfl_down(ss, o);
  }
  __shared__ float red[8];
  const int lane = t & 63, wv = t >> 6;
  if (lane == 0) { red[wv] = s; red[4 + wv] = ss; }
  __syncthreads();
  s = red[0] + red[1] + red[2] + red[3];
  ss = red[4] + red[5] + red[6] + red[7];
  const float mu = s * (1.0f / 1024.0f);
  const float rstd = rsqrtf(ss * (1.0f / 1024.0f) - mu * mu + 1e-5f);
  const float4 w4 = ((const float4*)wgt)[t];
  bf16x4 o;
  o[0] = (__bf16)((v.x - mu) * rstd * w4.x);
  o[1] = (__bf16)((v.y - mu) * rstd * w4.y);
  o[2] = (__bf16)((v.z - mu) * rstd * w4.z);
  o[3] = (__bf16)((v.w - mu) * rstd * w4.w);
  ((bf16x4*)(xn + (size_t)row * DDIM))[t] = o;
}

// ---------------- fp32 -> bf16 weight cast ----------------
__global__ __launch_bounds__(256) void cast_kernel(const float* __restrict__ src,
                                                   __bf16* __restrict__ dst, int n4) {
  const int i = blockIdx.x * 256 + threadIdx.x;
  if (i < n4) {
    const float4 v = ((const float4*)src)[i];
    bf16x4 o;
    o[0] = (__bf16)v.x; o[1] = (__bf16)v.y; o[2] = (__bf16)v.z; o[3] = (__bf16)v.w;
    ((bf16x4*)dst)[i] = o;
  }
}

// ------------- small m97-style GEMM (for the skinny q/k columns) -------------
__global__ __launch_bounds__(256) void gemm_bt(const __bf16* __restrict__ A,
                                               const __bf16* __restrict__ Bt,
                                               __bf16* __restrict__ Cout,
                                               int Ndim, int Kdim, int coff) {
  __shared__ __bf16 As[128 * 32];
  __shared__ __bf16 Bs[128 * 32];
  const int t = threadIdx.x;
  const int lane = t & 63;
  const int w = t >> 6;
  const int wm = w >> 1, wn = w & 1;
  const int m0 = blockIdx.x * 128;
  const int n0 = blockIdx.y * 128;

  f32x4 acc[4][4] = {};

  const int cA = w * 2;
  const int sr = cA * 16 + (lane >> 2);
  const int sc = (lane & 3) * 8;
  const __bf16* gA0 = A + (size_t)(m0 + sr) * Kdim + sc;
  const __bf16* gA1 = A + (size_t)(m0 + sr + 16) * Kdim + sc;
  const __bf16* gB0 = Bt + (size_t)(n0 + sr) * Kdim + sc;
  const __bf16* gB1 = Bt + (size_t)(n0 + sr + 16) * Kdim + sc;
  __bf16* lA0 = As + cA * 512;
  __bf16* lA1 = As + (cA + 1) * 512;
  __bf16* lB0 = Bs + cA * 512;
  __bf16* lB1 = Bs + (cA + 1) * 512;

  const int lr = lane & 15;
  const int lk = (lane >> 4) * 8;
  const int nk = Kdim >> 5;

  for (int kt = 0; kt < nk; ++kt) {
    __syncthreads();
    const int ko = kt * 32;
    async16(gA0 + ko, lA0);
    async16(gA1 + ko, lA1);
    async16(gB0 + ko, lB0);
    async16(gB1 + ko, lB1);
    __syncthreads();
    bf16x8 a[4], b[4];
    #pragma unroll
    for (int i = 0; i < 4; ++i)
      a[i] = *(const bf16x8*)&As[(wm * 64 + i * 16 + lr) * 32 + lk];
    #pragma unroll
    for (int i = 0; i < 4; ++i)
      b[i] = *(const bf16x8*)&Bs[(wn * 64 + i * 16 + lr) * 32 + lk];
    #pragma unroll
    for (int i = 0; i < 4; ++i)
      #pragma unroll
      for (int j = 0; j < 4; ++j)
        acc[i][j] = __builtin_amdgcn_mfma_f32_16x16x32_bf16(a[i], b[j], acc[i][j], 0, 0, 0);
  }

  #pragma unroll
  for (int i = 0; i < 4; ++i) {
    const int rbase = m0 + wm * 64 + i * 16 + ((lane >> 4) << 2);
    #pragma unroll
    for (int j = 0; j < 4; ++j) {
      const int col = coff + n0 + wn * 64 + j * 16 + (lane & 15);
      #pragma unroll
      for (int r = 0; r < 4; ++r)
        Cout[(size_t)(rbase + r) * Ndim + col] = (__bf16)acc[i][j][r];
    }
  }
}

// ------- full-tile register-pipelined MFMA GEMM, C = A * Bt^T --------
// BM x 256 tile, BK=64, 512 threads (8 waves, 2Mx4N), double-buffered
// XOR-swizzled LDS. Per K-tile: [stage 8 DMAs for t+1] -> [all 24 ds_reads]
// -> [MFMA kq0 | MFMA kq1] (compiler inserts counted lgkm waits so kq1's
// LDS service overlaps kq0's MFMA) -> bare vmcnt(0) -> raw s_barrier.
// No "memory"-clobbered asm in the loop (would force drain-0 at every
// barrier); ordering pinned via sched_barrier(0).
// EPI=0: bf16 store at col offset coff. EPI=1: fp32 store = resid + acc.
template <int BM, int EPI>
__global__ __launch_bounds__(512, 2) void gemmrp(const __bf16* __restrict__ A,
                                                 const __bf16* __restrict__ Bt,
                                                 void* __restrict__ Cout,
                                                 const float* __restrict__ resid,
                                                 int Ndim, int Kdim, int ntiles, int coff) {
  constexpr int MF = BM / 32;          // A-frags per kq (8 / 4)
  constexpr int ASZ = BM * 128;        // bytes per A buffer
  constexpr int BSZ = 256 * 128;       // bytes per B buffer
  constexpr int CA = BM / 64;          // A stage chunks per tile (4 / 2)
  __shared__ alignas(16) __bf16 As[2 * BM * 64];
  __shared__ alignas(16) __bf16 Bs[2 * 256 * 64];

  const int tid = threadIdx.x;
  const int lane = tid & 63;
  const int w = tid >> 6;
  const int wm = w >> 2, wn = w & 3;

  const int qq = gridDim.x >> 3;
  const int wgid = (blockIdx.x & 7) * qq + (blockIdx.x >> 3);
  const int m0 = (wgid / ntiles) * BM;
  const int n0 = (wgid % ntiles) * 256;

  f32x4 acc[MF][4] = {};

  // staging map: LDS(row, c16) holds global(row, c16 ^ ((row&7)<<4))
  const int rowS = tid >> 3;
  const int kbS = ((tid & 7) * 16) ^ ((rowS & 7) << 4);
  const size_t K2 = (size_t)Kdim * 2;
  const char* gA = (const char*)A + (size_t)(m0 + rowS) * K2 + kbS;
  const char* gB = (const char*)Bt + (size_t)(n0 + rowS) * K2 + kbS;
  char* lA = (char*)As;
  char* lB = (char*)Bs;

  const int lr = lane & 15;
  const int hi = lane >> 4;
  const int kxor = (lr & 7) << 4;
  const int k0 = (hi * 16) ^ kxor;           // kq=0 byte offset
  const int k1 = ((hi * 16) | 64) ^ kxor;    // kq=1 byte offset
  const int rowA = (wm * (BM / 2) + lr) * 128;
  const int rowB = (wn * 64 + lr) * 128;
  const int NT = Kdim >> 6;

  // prologue: stage tile 0 into buf 0
  #pragma unroll
  for (int c = 0; c < CA; ++c) async16(gA + (size_t)c * 64 * K2, lA + c * 8192 + tid * 16);
  #pragma unroll
  for (int c = 0; c < 4; ++c) async16(gB + (size_t)c * 64 * K2, lB + c * 8192 + tid * 16);
  SCHED_PIN();
  S_VM0_BARE();
  __builtin_amdgcn_s_barrier();
  SCHED_PIN();

  for (int t = 0; t < NT; ++t) {
    const int buf = t & 1;
    const char* pA0 = lA + buf * ASZ + rowA + k0;
    const char* pA1 = lA + buf * ASZ + rowA + k1;
    const char* pB0 = lB + buf * BSZ + rowB + k0;
    const char* pB1 = lB + buf * BSZ + rowB + k1;

    // -------- group 1: stage tile t+1 into buf^1 (max flight) --------
    if (t + 1 < NT) {
      const char* gAt = gA + (size_t)(t + 1) * 128;
      const char* gBt = gB + (size_t)(t + 1) * 128;
      char* lAd = lA + (buf ^ 1) * ASZ + tid * 16;
      char* lBd = lB + (buf ^ 1) * BSZ + tid * 16;
      #pragma unroll
      for (int c = 0; c < CA; ++c) async16(gAt + (size_t)c * 64 * K2, lAd + c * 8192);
      #pragma unroll
      for (int c = 0; c < 4; ++c) async16(gBt + (size_t)c * 64 * K2, lBd + c * 8192);
    }
    SCHED_PIN();

    // -------- group 2: all fragment ds_reads for tile t --------
    bf16x8 b0[4], a0[MF], b1[4], a1[MF];
    #pragma unroll
    for (int ni = 0; ni < 4; ++ni) b0[ni] = *(const bf16x8*)(pB0 + ni * 2048);
    #pragma unroll
    for (int mi = 0; mi < MF; ++mi) a0[mi] = *(const bf16x8*)(pA0 + mi * 2048);
    #pragma unroll
    for (int ni = 0; ni < 4; ++ni) b1[ni] = *(const bf16x8*)(pB1 + ni * 2048);
    #pragma unroll
    for (int mi = 0; mi < MF; ++mi) a1[mi] = *(const bf16x8*)(pA1 + mi * 2048);
    SCHED_PIN();

    // -------- MFMA kq0 (compiler-inserted counted lgkm wait) --------
    __builtin_amdgcn_s_setprio(1);
    #pragma unroll
    for (int mi = 0; mi < MF; ++mi)
      #pragma unroll
      for (int ni = 0; ni < 4; ++ni)
        acc[mi][ni] = __builtin_amdgcn_mfma_f32_16x16x32_bf16(a0[mi], b0[ni], acc[mi][ni], 0, 0, 0);
    // -------- MFMA kq1 --------
    #pragma unroll
    for (int mi = 0; mi < MF; ++mi)
      #pragma unroll
      for (int ni = 0; ni < 4; ++ni)
        acc[mi][ni] = __builtin_amdgcn_mfma_f32_16x16x32_bf16(a1[mi], b1[ni], acc[mi][ni], 0, 0, 0);
    __builtin_amdgcn_s_setprio(0);
    SCHED_PIN();

    // tile boundary: next tile's DMAs must have landed before any wave
    // reads buf^1. Our own ds_reads were all consumed by MFMAs above, so
    // the barrier alone closes the cross-wave WAR on buf.
    if (t + 1 < NT) {
      S_VM0_BARE();
      __builtin_amdgcn_s_barrier();
    }
    SCHED_PIN();
  }

  // epilogue: C/D layout row=(lane>>4)*4+reg, col=lane&15
  #pragma unroll
  for (int mi = 0; mi < MF; ++mi) {
    const int rbase = m0 + wm * (BM / 2) + mi * 16 + ((lane >> 4) << 2);
    #pragma unroll
    for (int ni = 0; ni < 4; ++ni) {
      const int col = coff + n0 + wn * 64 + ni * 16 + (lane & 15);
      #pragma unroll
      for (int r = 0; r < 4; ++r) {
        const size_t off = (size_t)(rbase + r) * Ndim + col;
        if constexpr (EPI == 0) ((__bf16*)Cout)[off] = (__bf16)acc[mi][ni][r];
        else                    ((float*)Cout)[off] = resid[off] + acc[mi][ni][r];
      }
    }
  }
}

// ---------------- GEGLU: gl / v from h ----------------
__global__ __launch_bounds__(256) void geglu_kernel(const __bf16* __restrict__ h,
                                                    __bf16* __restrict__ fused,
                                                    __bf16* __restrict__ vbuf) {
  const int idx = blockIdx.x * 256 + threadIdx.x;
  const int row = idx >> 8;
  const int col = (idx & 255) * 8;
  const bf16x8 lin = *(const bf16x8*)&h[(size_t)row * NEXP + 256 + col];
  const bf16x8 pre = *(const bf16x8*)&h[(size_t)row * NEXP + 2304 + col];
  bf16x8 o;
  #pragma unroll
  for (int j = 0; j < 8; ++j) {
    const float p = (float)pre[j];
    const float g = 0.5f * p * (1.0f + erff(p * 0.70710678118f));
    o[j] = (__bf16)((float)lin[j] * g);
  }
  if (col < 1024)
    *(bf16x8*)&fused[(size_t)row * EDIM + col] = o;
  else
    *(bf16x8*)&vbuf[(size_t)row * 1024 + (col - 1024)] = o;
}

// ---------------- sliding-window attention (W=32), 1 wave per (b,head,s) ----------
__global__ __launch_bounds__(256) void attn_kernel(const __bf16* __restrict__ h,
                                                   const __bf16* __restrict__ vbuf,
                                                   __bf16* __restrict__ fused,
                                                   const float* __restrict__ pbm) {
  const int gw = blockIdx.x * 4 + (threadIdx.x >> 6);
  const int lane = threadIdx.x & 63;
  const int s = gw & 1023;
  const int head = (gw >> 10) & 3;
  const int b = gw >> 12;

  const float p = pbm[0];
  const float sp = (p > 20.0f) ? p : log1pf(expf(p));

  const size_t rowq = (size_t)(b * 1024 + s);
  float q[32];
  const bf16x8* qp = (const bf16x8*)&h[rowq * NEXP + head * 32];
  #pragma unroll
  for (int c = 0; c < 4; ++c) {
    const bf16x8 tq = qp[c];
    #pragma unroll
    for (int j = 0; j < 8; ++j) q[c * 8 + j] = (float)tq[j];
  }

  const int jj = lane & 31;
  const int sk = s - 31 + jj;
  const int skc = (sk < 0) ? 0 : sk;
  float dot = 0.0f;
  const bf16x8* kp = (const bf16x8*)&h[(size_t)(b * 1024 + skc) * NEXP + 128 + head * 32];
  #pragma unroll
  for (int c = 0; c < 4; ++c) {
    const bf16x8 tk = kp[c];
    #pragma unroll
    for (int j = 0; j < 8; ++j) dot += q[c * 8 + j] * (float)tk[j];
  }
  float score = (sk >= 0) ? (dot * 0.1767766953f + sp * (float)(sk - s)) : -1e30f;

  float mx = score;
  #pragma unroll
  for (int o = 16; o > 0; o >>= 1) mx = fmaxf(mx, __shfl_xor(mx, o));
  const float wgt = expf(score - mx);
  float sum = wgt;
  #pragma unroll
  for (int o = 16; o > 0; o >>= 1) sum += __shfl_xor(sum, o);

  float a0 = 0.f, a1 = 0.f, a2 = 0.f, a3 = 0.f;
  const __bf16* vb = vbuf + head * 256 + lane * 4;
  for (int j2 = 0; j2 < 32; ++j2) {
    const int sv = s - 31 + j2;
    if (sv < 0) continue;
    const float wj = __shfl(wgt, j2);
    const bf16x4 vv = *(const bf16x4*)&vb[(size_t)(b * 1024 + sv) * 1024];
    a0 += wj * (float)vv[0];
    a1 += wj * (float)vv[1];
    a2 += wj * (float)vv[2];
    a3 += wj * (float)vv[3];
  }
  const float inv = 1.0f / sum;
  bf16x4 o;
  o[0] = (__bf16)(a0 * inv);
  o[1] = (__bf16)(a1 * inv);
  o[2] = (__bf16)(a2 * inv);
  o[3] = (__bf16)(a3 * inv);
  *(bf16x4*)&fused[rowq * EDIM + 1024 + head * 256 + lane * 4] = o;
}

// ---------------- host launch ----------------
extern "C" void kernel_launch(void* const* d_in, const int* in_sizes, int n_in,
                              void* d_out, int out_size, void* d_ws, size_t ws_size,
                              hipStream_t stream) {
  const float* x = (const float*)d_in[0];
  const float* norm_w = (const float*)d_in[2];
  const float* expand_w = (const float*)d_in[3];
  const float* project_w = (const float*)d_in[4];
  const float* pbm = (const float*)d_in[5];
  float* out = (float*)d_out;

  char* ws = (char*)d_ws;
  __bf16* xn    = (__bf16*)(ws);                 // 16,777,216
  __bf16* wexp  = (__bf16*)(ws + 16777216);      //  8,912,896
  __bf16* wproj = (__bf16*)(ws + 25690112);      //  4,194,304
  __bf16* h     = (__bf16*)(ws + 29884416);      // 71,303,168
  __bf16* fused = (__bf16*)(ws + 101187584);     // 33,554,432
  __bf16* vbuf  = (__bf16*)(ws + 134742016);     // 16,777,216

  ln_kernel<<<MROWS, 256, 0, stream>>>(x, norm_w, xn);
  cast_kernel<<<4352, 256, 0, stream>>>(expand_w, wexp, 4456448 / 4);
  cast_kernel<<<2048, 256, 0, stream>>>(project_w, wproj, 2097152 / 4);
  // q/k columns: M=8192, N=256, K=1024
  gemm_bt<<<dim3(64, 2), 256, 0, stream>>>(xn, wexp, h, NEXP, DDIM, 0);
  // lin|pre columns: M=8192, N=4096, K=1024 -> 512 blocks (2.0 rounds)
  gemmrp<256, 0><<<512, 512, 0, stream>>>(xn, wexp + 256 * DDIM, (void*)h, nullptr,
                                          NEXP, DDIM, 16, 256);
  geglu_kernel<<<MROWS, 256, 0, stream>>>(h, fused, vbuf);
  attn_kernel<<<MROWS, 256, 0, stream>>>(h, vbuf, fused, pbm);
  // project: M=8192, N=1024, K=2048 -> 256 blocks (1.0 round)
  gemmrp<128, 1><<<256, 512, 0, stream>>>(fused, wproj, (void*)out, x, DDIM, EDIM, 4, 0);
}

// Round 8
// 221.899 us; speedup vs baseline: 1.1241x; 1.1241x over previous
//
#include <hip/hip_runtime.h>
#include <hip/hip_bf16.h>
#include <hip/hip_fp8.h>

typedef __bf16 bf16x8 __attribute__((ext_vector_type(8)));
typedef __bf16 bf16x4 __attribute__((ext_vector_type(4)));
typedef float f32x4 __attribute__((ext_vector_type(4)));
typedef unsigned int u32;
typedef __attribute__((address_space(3))) u32 lds_u32_t;
typedef __attribute__((address_space(1))) u32 glb_u32_t;

#define MROWS 8192      // B*S
#define NEXP 4352       // 2*QK + 2*EXPAND
#define DDIM 1024
#define EDIM 2048

#define S_BAR() asm volatile("s_barrier" ::: "memory")
#define S_VM0() asm volatile("s_waitcnt vmcnt(0)" ::: "memory")
#define SCHED_PIN() __builtin_amdgcn_sched_barrier(0)

__device__ __forceinline__ void async16(const void* g, void* l) {
  __builtin_amdgcn_global_load_lds((const glb_u32_t*)g, (lds_u32_t*)l, 16, 0, 0);
}

__device__ __forceinline__ u32 pack4_e4m3(float f0, float f1, float f2, float f3) {
  __hip_fp8_e4m3 a(f0), b(f1), c(f2), d(f3);
  return (u32)a.__x | ((u32)b.__x << 8) | ((u32)c.__x << 16) | ((u32)d.__x << 24);
}

// ---------------- LayerNorm + bf16 cast + fp8 cast ----------------
__global__ __launch_bounds__(256) void ln_kernel(const float* __restrict__ x,
                                                 const float* __restrict__ wgt,
                                                 __bf16* __restrict__ xn,
                                                 u32* __restrict__ xn8) {
  const int row = blockIdx.x;
  const int t = threadIdx.x;
  const float4 v = ((const float4*)(x + (size_t)row * DDIM))[t];
  float s = v.x + v.y + v.z + v.w;
  float ss = v.x * v.x + v.y * v.y + v.z * v.z + v.w * v.w;
  #pragma unroll
  for (int o = 32; o > 0; o >>= 1) {
    s += __shfl_down(s, o);
    ss += __shfl_down(ss, o);
  }
  __shared__ float red[8];
  const int lane = t & 63, wv = t >> 6;
  if (lane == 0) { red[wv] = s; red[4 + wv] = ss; }
  __syncthreads();
  s = red[0] + red[1] + red[2] + red[3];
  ss = red[4] + red[5] + red[6] + red[7];
  const float mu = s * (1.0f / 1024.0f);
  const float rstd = rsqrtf(ss * (1.0f / 1024.0f) - mu * mu + 1e-5f);
  const float4 w4 = ((const float4*)wgt)[t];
  const float f0 = (v.x - mu) * rstd * w4.x;
  const float f1 = (v.y - mu) * rstd * w4.y;
  const float f2 = (v.z - mu) * rstd * w4.z;
  const float f3 = (v.w - mu) * rstd * w4.w;
  bf16x4 o;
  o[0] = (__bf16)f0; o[1] = (__bf16)f1; o[2] = (__bf16)f2; o[3] = (__bf16)f3;
  ((bf16x4*)(xn + (size_t)row * DDIM))[t] = o;
  xn8[row * 256 + t] = pack4_e4m3(f0, f1, f2, f3);
}

// ---------------- fp32 -> bf16 weight cast ----------------
__global__ __launch_bounds__(256) void cast_kernel(const float* __restrict__ src,
                                                   __bf16* __restrict__ dst, int n4) {
  const int i = blockIdx.x * 256 + threadIdx.x;
  if (i < n4) {
    const float4 v = ((const float4*)src)[i];
    bf16x4 o;
    o[0] = (__bf16)v.x; o[1] = (__bf16)v.y; o[2] = (__bf16)v.z; o[3] = (__bf16)v.w;
    ((bf16x4*)dst)[i] = o;
  }
}

// ---------------- fp32 -> fp8 weight cast (pre-scaled) ----------------
__global__ __launch_bounds__(256) void cast8_kernel(const float* __restrict__ src,
                                                    u32* __restrict__ dst, int n4, float scale) {
  const int i = blockIdx.x * 256 + threadIdx.x;
  if (i < n4) {
    const float4 v = ((const float4*)src)[i];
    dst[i] = pack4_e4m3(v.x * scale, v.y * scale, v.z * scale, v.w * scale);
  }
}

// ------------- small m97-style bf16 GEMM (skinny q/k columns) -------------
__global__ __launch_bounds__(256) void gemm_bt(const __bf16* __restrict__ A,
                                               const __bf16* __restrict__ Bt,
                                               __bf16* __restrict__ Cout,
                                               int Ndim, int Kdim, int coff) {
  __shared__ __bf16 As[128 * 32];
  __shared__ __bf16 Bs[128 * 32];
  const int t = threadIdx.x;
  const int lane = t & 63;
  const int w = t >> 6;
  const int wm = w >> 1, wn = w & 1;
  const int m0 = blockIdx.x * 128;
  const int n0 = blockIdx.y * 128;

  f32x4 acc[4][4] = {};

  const int cA = w * 2;
  const int sr = cA * 16 + (lane >> 2);
  const int sc = (lane & 3) * 8;
  const __bf16* gA0 = A + (size_t)(m0 + sr) * Kdim + sc;
  const __bf16* gA1 = A + (size_t)(m0 + sr + 16) * Kdim + sc;
  const __bf16* gB0 = Bt + (size_t)(n0 + sr) * Kdim + sc;
  const __bf16* gB1 = Bt + (size_t)(n0 + sr + 16) * Kdim + sc;
  __bf16* lA0 = As + cA * 512;
  __bf16* lA1 = As + (cA + 1) * 512;
  __bf16* lB0 = Bs + cA * 512;
  __bf16* lB1 = Bs + (cA + 1) * 512;

  const int lr = lane & 15;
  const int lk = (lane >> 4) * 8;
  const int nk = Kdim >> 5;

  for (int kt = 0; kt < nk; ++kt) {
    __syncthreads();
    const int ko = kt * 32;
    async16(gA0 + ko, lA0);
    async16(gA1 + ko, lA1);
    async16(gB0 + ko, lB0);
    async16(gB1 + ko, lB1);
    __syncthreads();
    bf16x8 a[4], b[4];
    #pragma unroll
    for (int i = 0; i < 4; ++i)
      a[i] = *(const bf16x8*)&As[(wm * 64 + i * 16 + lr) * 32 + lk];
    #pragma unroll
    for (int i = 0; i < 4; ++i)
      b[i] = *(const bf16x8*)&Bs[(wn * 64 + i * 16 + lr) * 32 + lk];
    #pragma unroll
    for (int i = 0; i < 4; ++i)
      #pragma unroll
      for (int j = 0; j < 4; ++j)
        acc[i][j] = __builtin_amdgcn_mfma_f32_16x16x32_bf16(a[i], b[j], acc[i][j], 0, 0, 0);
  }

  #pragma unroll
  for (int i = 0; i < 4; ++i) {
    const int rbase = m0 + wm * 64 + i * 16 + ((lane >> 4) << 2);
    #pragma unroll
    for (int j = 0; j < 4; ++j) {
      const int col = coff + n0 + wn * 64 + j * 16 + (lane & 15);
      #pragma unroll
      for (int r = 0; r < 4; ++r)
        Cout[(size_t)(rbase + r) * Ndim + col] = (__bf16)acc[i][j][r];
    }
  }
}

// ---------------- fp8 MFMA GEMM, C = A * Bt^T ----------------
// BM x 256 tile, BK=64 (64B/row), 512 threads (8 waves, 2Mx4N), wave-tile
// (BM/2)x64, acc = MF*4*4 <= 64 f32 -> <=128 VGPR -> 2 blocks/CU
// (cross-block TLP hides LDS/DMA). LDS swizzle at 16B units:
// phys_unit = unit ^ ((row>>1)&3) -> 2-way conflicts (free), DMA-compatible.
// EPI=0: bf16 store (acc*scl) at col offset coff. EPI=1: fp32 resid + acc*scl.
template <int BM, int EPI>
__global__ __launch_bounds__(512, 4) void gemmf8(const char* __restrict__ A8,
                                                 const char* __restrict__ B8,
                                                 void* __restrict__ Cout,
                                                 const float* __restrict__ resid,
                                                 int Ndim, int Kdim, int ntiles,
                                                 int coff, float scl) {
  constexpr int MF = BM / 32;          // m-frags per wave (4 / 2)
  constexpr int ASZ = BM * 64;         // bytes per A buffer
  constexpr int BSZ = 256 * 64;        // bytes per B buffer
  __shared__ alignas(16) char As[2 * ASZ];
  __shared__ alignas(16) char Bs[2 * BSZ];

  const int tid = threadIdx.x;
  const int lane = tid & 63;
  const int w = tid >> 6;
  const int wm = w >> 2, wn = w & 3;

  const int qq = gridDim.x >> 3;
  const int wgid = (blockIdx.x & 7) * qq + (blockIdx.x >> 3);
  const int m0 = (wgid / ntiles) * BM;
  const int n0 = (wgid % ntiles) * 256;

  f32x4 acc[MF][4] = {};

  // staging: thread covers (rowS, phys unit uS); source uses logical unit
  const int rowS = (tid >> 2) & 127;
  const int uS = tid & 3;
  const int luS = uS ^ ((rowS >> 1) & 3);
  const char* gA = A8 + (size_t)(m0 + rowS) * Kdim + luS * 16;
  const char* gB = B8 + (size_t)(n0 + rowS) * Kdim + luS * 16;
  char* lA = (char*)As;
  char* lB = (char*)Bs;

  const int lr = lane & 15;
  const int hi = lane >> 4;
  const int sw = (lr >> 1) & 3;
  // kq byte-column c = kq*32 + hi*8 -> unit c>>4, in-unit (hi&1)*8
  const int kof0 = ((((hi >> 1)) ^ sw) << 4) + (hi & 1) * 8;
  const int kof1 = (((2 + (hi >> 1)) ^ sw) << 4) + (hi & 1) * 8;
  const int rowA = (wm * (BM / 2) + lr) * 64;
  const int rowB = (wn * 64 + lr) * 64;
  const int NT = Kdim >> 6;

  // prologue: stage tile 0 into buf 0
  if constexpr (BM == 128) {
    async16(gA, lA + tid * 16);
  } else {  // BM == 64: A tile is 4KB, threads 0-255 stage it
    if (tid < 256) async16(gA, lA + tid * 16);
  }
  async16(gB, lB + tid * 16);
  async16(gB + (size_t)128 * Kdim, lB + 8192 + tid * 16);
  S_VM0();
  S_BAR();

  for (int t = 0; t < NT; ++t) {
    const int buf = t & 1;
    const char* pA = lA + buf * ASZ + rowA;
    const char* pB = lB + buf * BSZ + rowB;

    // -------- group 1: kq0 reads --------
    long a0[MF], b0[4], a1[MF], b1[4];
    #pragma unroll
    for (int ni = 0; ni < 4; ++ni) b0[ni] = *(const long*)(pB + ni * 1024 + kof0);
    #pragma unroll
    for (int mi = 0; mi < MF; ++mi) a0[mi] = *(const long*)(pA + mi * 1024 + kof0);
    SCHED_PIN();
    // -------- group 2: kq1 reads --------
    #pragma unroll
    for (int ni = 0; ni < 4; ++ni) b1[ni] = *(const long*)(pB + ni * 1024 + kof1);
    #pragma unroll
    for (int mi = 0; mi < MF; ++mi) a1[mi] = *(const long*)(pA + mi * 1024 + kof1);
    SCHED_PIN();
    // -------- group 3: stage tile t+1 into buf^1 --------
    if (t + 1 < NT) {
      const char* gAt = gA + (size_t)(t + 1) * 64;
      const char* gBt = gB + (size_t)(t + 1) * 64;
      char* lAd = lA + (buf ^ 1) * ASZ + tid * 16;
      char* lBd = lB + (buf ^ 1) * BSZ + tid * 16;
      if constexpr (BM == 128) {
        async16(gAt, lAd);
      } else {
        if (tid < 256) async16(gAt, lAd);
      }
      async16(gBt, lBd);
      async16(gBt + (size_t)128 * Kdim, lBd + 8192);
    }
    SCHED_PIN();
    // -------- MFMA kq0 --------
    __builtin_amdgcn_s_setprio(1);
    #pragma unroll
    for (int mi = 0; mi < MF; ++mi)
      #pragma unroll
      for (int ni = 0; ni < 4; ++ni)
        acc[mi][ni] = __builtin_amdgcn_mfma_f32_16x16x32_fp8_fp8(a0[mi], b0[ni], acc[mi][ni], 0, 0, 0);
    __builtin_amdgcn_s_setprio(0);
    SCHED_PIN();
    // -------- MFMA kq1 --------
    __builtin_amdgcn_s_setprio(1);
    #pragma unroll
    for (int mi = 0; mi < MF; ++mi)
      #pragma unroll
      for (int ni = 0; ni < 4; ++ni)
        acc[mi][ni] = __builtin_amdgcn_mfma_f32_16x16x32_fp8_fp8(a1[mi], b1[ni], acc[mi][ni], 0, 0, 0);
    __builtin_amdgcn_s_setprio(0);
    SCHED_PIN();
    if (t + 1 < NT) S_VM0();
    S_BAR();
  }

  // epilogue: C/D layout row=(lane>>4)*4+reg, col=lane&15
  #pragma unroll
  for (int mi = 0; mi < MF; ++mi) {
    const int rbase = m0 + wm * (BM / 2) + mi * 16 + ((lane >> 4) << 2);
    #pragma unroll
    for (int ni = 0; ni < 4; ++ni) {
      const int col = coff + n0 + wn * 64 + ni * 16 + (lane & 15);
      #pragma unroll
      for (int r = 0; r < 4; ++r) {
        const size_t off = (size_t)(rbase + r) * Ndim + col;
        if constexpr (EPI == 0) ((__bf16*)Cout)[off] = (__bf16)(acc[mi][ni][r] * scl);
        else                    ((float*)Cout)[off] = resid[off] + acc[mi][ni][r] * scl;
      }
    }
  }
}

// ---------------- GEGLU: gl (fp8) / v (bf16) from h ----------------
__global__ __launch_bounds__(256) void geglu_kernel(const __bf16* __restrict__ h,
                                                    char* __restrict__ fused8,
                                                    __bf16* __restrict__ vbuf) {
  const int idx = blockIdx.x * 256 + threadIdx.x;
  const int row = idx >> 8;
  const int col = (idx & 255) * 8;
  const bf16x8 lin = *(const bf16x8*)&h[(size_t)row * NEXP + 256 + col];
  const bf16x8 pre = *(const bf16x8*)&h[(size_t)row * NEXP + 2304 + col];
  float g[8];
  #pragma unroll
  for (int j = 0; j < 8; ++j) {
    const float p = (float)pre[j];
    const float gg = 0.5f * p * (1.0f + erff(p * 0.70710678118f));
    g[j] = (float)lin[j] * gg;
  }
  if (col < 1024) {
    u32 w0 = pack4_e4m3(g[0], g[1], g[2], g[3]);
    u32 w1 = pack4_e4m3(g[4], g[5], g[6], g[7]);
    u32* dst = (u32*)&fused8[(size_t)row * EDIM + col];
    dst[0] = w0; dst[1] = w1;
  } else {
    bf16x8 o;
    #pragma unroll
    for (int j = 0; j < 8; ++j) o[j] = (__bf16)g[j];
    *(bf16x8*)&vbuf[(size_t)row * 1024 + (col - 1024)] = o;
  }
}

// ---------------- sliding-window attention (W=32), 1 wave per (b,head,s) ----------
__global__ __launch_bounds__(256) void attn_kernel(const __bf16* __restrict__ h,
                                                   const __bf16* __restrict__ vbuf,
                                                   char* __restrict__ fused8,
                                                   const float* __restrict__ pbm) {
  const int gw = blockIdx.x * 4 + (threadIdx.x >> 6);
  const int lane = threadIdx.x & 63;
  const int s = gw & 1023;
  const int head = (gw >> 10) & 3;
  const int b = gw >> 12;

  const float p = pbm[0];
  const float sp = (p > 20.0f) ? p : log1pf(expf(p));

  const size_t rowq = (size_t)(b * 1024 + s);
  float q[32];
  const bf16x8* qp = (const bf16x8*)&h[rowq * NEXP + head * 32];
  #pragma unroll
  for (int c = 0; c < 4; ++c) {
    const bf16x8 tq = qp[c];
    #pragma unroll
    for (int j = 0; j < 8; ++j) q[c * 8 + j] = (float)tq[j];
  }

  const int jj = lane & 31;
  const int sk = s - 31 + jj;
  const int skc = (sk < 0) ? 0 : sk;
  float dot = 0.0f;
  const bf16x8* kp = (const bf16x8*)&h[(size_t)(b * 1024 + skc) * NEXP + 128 + head * 32];
  #pragma unroll
  for (int c = 0; c < 4; ++c) {
    const bf16x8 tk = kp[c];
    #pragma unroll
    for (int j = 0; j < 8; ++j) dot += q[c * 8 + j] * (float)tk[j];
  }
  float score = (sk >= 0) ? (dot * 0.1767766953f + sp * (float)(sk - s)) : -1e30f;

  float mx = score;
  #pragma unroll
  for (int o = 16; o > 0; o >>= 1) mx = fmaxf(mx, __shfl_xor(mx, o));
  const float wgt = expf(score - mx);
  float sum = wgt;
  #pragma unroll
  for (int o = 16; o > 0; o >>= 1) sum += __shfl_xor(sum, o);

  float a0 = 0.f, a1 = 0.f, a2 = 0.f, a3 = 0.f;
  const __bf16* vb = vbuf + head * 256 + lane * 4;
  for (int j2 = 0; j2 < 32; ++j2) {
    const int sv = s - 31 + j2;
    if (sv < 0) continue;
    const float wj = __shfl(wgt, j2);
    const bf16x4 vv = *(const bf16x4*)&vb[(size_t)(b * 1024 + sv) * 1024];
    a0 += wj * (float)vv[0];
    a1 += wj * (float)vv[1];
    a2 += wj * (float)vv[2];
    a3 += wj * (float)vv[3];
  }
  const float inv = 1.0f / sum;
  *(u32*)&fused8[rowq * EDIM + 1024 + head * 256 + lane * 4] =
      pack4_e4m3(a0 * inv, a1 * inv, a2 * inv, a3 * inv);
}

// ---------------- host launch ----------------
extern "C" void kernel_launch(void* const* d_in, const int* in_sizes, int n_in,
                              void* d_out, int out_size, void* d_ws, size_t ws_size,
                              hipStream_t stream) {
  const float* x = (const float*)d_in[0];
  const float* norm_w = (const float*)d_in[2];
  const float* expand_w = (const float*)d_in[3];
  const float* project_w = (const float*)d_in[4];
  const float* pbm = (const float*)d_in[5];
  float* out = (float*)d_out;

  char* ws = (char*)d_ws;
  __bf16* xn    = (__bf16*)(ws);                  // 16,777,216
  u32*    xn8   = (u32*)(ws + 16777216);          //  8,388,608
  __bf16* wqk   = (__bf16*)(ws + 25165824);       //    524,288 (q/k rows bf16)
  char*   wexp8 = (char*)(ws + 25690112);         //  4,194,304 (lin/pre rows fp8 x16)
  char*   wproj8= (char*)(ws + 29884416);         //  2,097,152 (fp8 x256)
  __bf16* h     = (__bf16*)(ws + 31981568);       // 71,303,168
  char*   fused8= (char*)(ws + 103284736);        // 16,777,216
  __bf16* vbuf  = (__bf16*)(ws + 120061952);      // 16,777,216
  // total 136,839,168 bytes

  ln_kernel<<<MROWS, 256, 0, stream>>>(x, norm_w, xn, xn8);
  cast_kernel<<<256, 256, 0, stream>>>(expand_w, wqk, 65536);
  cast8_kernel<<<4096, 256, 0, stream>>>(expand_w + 256 * DDIM, (u32*)wexp8, 1048576, 16.0f);
  cast8_kernel<<<2048, 256, 0, stream>>>(project_w, (u32*)wproj8, 524288, 256.0f);
  // q/k columns: M=8192, N=256, K=1024 (bf16, exact-ish)
  gemm_bt<<<dim3(64, 2), 256, 0, stream>>>(xn, wqk, h, NEXP, DDIM, 0);
  // lin|pre columns: M=8192, N=4096, K=1024 fp8 -> 64 x 16 = 1024 blocks
  gemmf8<128, 0><<<1024, 512, 0, stream>>>((const char*)xn8, wexp8, (void*)h, nullptr,
                                           NEXP, DDIM, 16, 256, 1.0f / 16.0f);
  geglu_kernel<<<MROWS, 256, 0, stream>>>(h, fused8, vbuf);
  attn_kernel<<<MROWS, 256, 0, stream>>>(h, vbuf, fused8, pbm);
  // project: M=8192, N=1024, K=2048 fp8 -> 128 x 4 = 512 blocks
  gemmf8<64, 1><<<512, 512, 0, stream>>>(fused8, wproj8, (void*)out, x,
                                         DDIM, EDIM, 4, 0, 1.0f / 256.0f);
}

// Round 9
// 172.293 us; speedup vs baseline: 1.4477x; 1.2879x over previous
//
#include <hip/hip_runtime.h>
#include <hip/hip_bf16.h>
#include <hip/hip_fp8.h>

typedef __bf16 bf16x8 __attribute__((ext_vector_type(8)));
typedef __bf16 bf16x4 __attribute__((ext_vector_type(4)));
typedef float f32x4 __attribute__((ext_vector_type(4)));
typedef unsigned int u32;
typedef __attribute__((address_space(3))) u32 lds_u32_t;
typedef __attribute__((address_space(1))) u32 glb_u32_t;

#define MROWS 8192      // B*S
#define NEXP 4352       // 2*QK + 2*EXPAND
#define DDIM 1024
#define EDIM 2048

#define S_BAR() asm volatile("s_barrier" ::: "memory")
#define S_VM0() asm volatile("s_waitcnt vmcnt(0)" ::: "memory")
#define SCHED_PIN() __builtin_amdgcn_sched_barrier(0)

__device__ __forceinline__ void async16(const void* g, void* l) {
  __builtin_amdgcn_global_load_lds((const glb_u32_t*)g, (lds_u32_t*)l, 16, 0, 0);
}

__device__ __forceinline__ u32 pack4_e4m3(float f0, float f1, float f2, float f3) {
  __hip_fp8_e4m3 a(f0), b(f1), c(f2), d(f3);
  return (u32)a.__x | ((u32)b.__x << 8) | ((u32)c.__x << 16) | ((u32)d.__x << 24);
}

// ---------------- LayerNorm + bf16 cast + fp8 cast ----------------
__global__ __launch_bounds__(256) void ln_kernel(const float* __restrict__ x,
                                                 const float* __restrict__ wgt,
                                                 __bf16* __restrict__ xn,
                                                 u32* __restrict__ xn8) {
  const int row = blockIdx.x;
  const int t = threadIdx.x;
  const float4 v = ((const float4*)(x + (size_t)row * DDIM))[t];
  float s = v.x + v.y + v.z + v.w;
  float ss = v.x * v.x + v.y * v.y + v.z * v.z + v.w * v.w;
  #pragma unroll
  for (int o = 32; o > 0; o >>= 1) {
    s += __shfl_down(s, o);
    ss += __shfl_down(ss, o);
  }
  __shared__ float red[8];
  const int lane = t & 63, wv = t >> 6;
  if (lane == 0) { red[wv] = s; red[4 + wv] = ss; }
  __syncthreads();
  s = red[0] + red[1] + red[2] + red[3];
  ss = red[4] + red[5] + red[6] + red[7];
  const float mu = s * (1.0f / 1024.0f);
  const float rstd = rsqrtf(ss * (1.0f / 1024.0f) - mu * mu + 1e-5f);
  const float4 w4 = ((const float4*)wgt)[t];
  const float f0 = (v.x - mu) * rstd * w4.x;
  const float f1 = (v.y - mu) * rstd * w4.y;
  const float f2 = (v.z - mu) * rstd * w4.z;
  const float f3 = (v.w - mu) * rstd * w4.w;
  bf16x4 o;
  o[0] = (__bf16)f0; o[1] = (__bf16)f1; o[2] = (__bf16)f2; o[3] = (__bf16)f3;
  ((bf16x4*)(xn + (size_t)row * DDIM))[t] = o;
  xn8[row * 256 + t] = pack4_e4m3(f0, f1, f2, f3);
}

// ---------------- fp32 -> bf16 weight cast ----------------
__global__ __launch_bounds__(256) void cast_kernel(const float* __restrict__ src,
                                                   __bf16* __restrict__ dst, int n4) {
  const int i = blockIdx.x * 256 + threadIdx.x;
  if (i < n4) {
    const float4 v = ((const float4*)src)[i];
    bf16x4 o;
    o[0] = (__bf16)v.x; o[1] = (__bf16)v.y; o[2] = (__bf16)v.z; o[3] = (__bf16)v.w;
    ((bf16x4*)dst)[i] = o;
  }
}

// ---------------- fp32 -> fp8 weight cast (pre-scaled) ----------------
__global__ __launch_bounds__(256) void cast8_kernel(const float* __restrict__ src,
                                                    u32* __restrict__ dst, int n4, float scale) {
  const int i = blockIdx.x * 256 + threadIdx.x;
  if (i < n4) {
    const float4 v = ((const float4*)src)[i];
    dst[i] = pack4_e4m3(v.x * scale, v.y * scale, v.z * scale, v.w * scale);
  }
}

// ------------- small m97-style bf16 GEMM (skinny q/k columns) -------------
__global__ __launch_bounds__(256) void gemm_bt(const __bf16* __restrict__ A,
                                               const __bf16* __restrict__ Bt,
                                               __bf16* __restrict__ Cout,
                                               int Ndim, int Kdim, int coff) {
  __shared__ __bf16 As[128 * 32];
  __shared__ __bf16 Bs[128 * 32];
  const int t = threadIdx.x;
  const int lane = t & 63;
  const int w = t >> 6;
  const int wm = w >> 1, wn = w & 1;
  const int m0 = blockIdx.x * 128;
  const int n0 = blockIdx.y * 128;

  f32x4 acc[4][4] = {};

  const int cA = w * 2;
  const int sr = cA * 16 + (lane >> 2);
  const int sc = (lane & 3) * 8;
  const __bf16* gA0 = A + (size_t)(m0 + sr) * Kdim + sc;
  const __bf16* gA1 = A + (size_t)(m0 + sr + 16) * Kdim + sc;
  const __bf16* gB0 = Bt + (size_t)(n0 + sr) * Kdim + sc;
  const __bf16* gB1 = Bt + (size_t)(n0 + sr + 16) * Kdim + sc;
  __bf16* lA0 = As + cA * 512;
  __bf16* lA1 = As + (cA + 1) * 512;
  __bf16* lB0 = Bs + cA * 512;
  __bf16* lB1 = Bs + (cA + 1) * 512;

  const int lr = lane & 15;
  const int lk = (lane >> 4) * 8;
  const int nk = Kdim >> 5;

  for (int kt = 0; kt < nk; ++kt) {
    __syncthreads();
    const int ko = kt * 32;
    async16(gA0 + ko, lA0);
    async16(gA1 + ko, lA1);
    async16(gB0 + ko, lB0);
    async16(gB1 + ko, lB1);
    __syncthreads();
    bf16x8 a[4], b[4];
    #pragma unroll
    for (int i = 0; i < 4; ++i)
      a[i] = *(const bf16x8*)&As[(wm * 64 + i * 16 + lr) * 32 + lk];
    #pragma unroll
    for (int i = 0; i < 4; ++i)
      b[i] = *(const bf16x8*)&Bs[(wn * 64 + i * 16 + lr) * 32 + lk];
    #pragma unroll
    for (int i = 0; i < 4; ++i)
      #pragma unroll
      for (int j = 0; j < 4; ++j)
        acc[i][j] = __builtin_amdgcn_mfma_f32_16x16x32_bf16(a[i], b[j], acc[i][j], 0, 0, 0);
  }

  #pragma unroll
  for (int i = 0; i < 4; ++i) {
    const int rbase = m0 + wm * 64 + i * 16 + ((lane >> 4) << 2);
    #pragma unroll
    for (int j = 0; j < 4; ++j) {
      const int col = coff + n0 + wn * 64 + j * 16 + (lane & 15);
      #pragma unroll
      for (int r = 0; r < 4; ++r)
        Cout[(size_t)(rbase + r) * Ndim + col] = (__bf16)acc[i][j][r];
    }
  }
}

// ---------------- fp8 MFMA GEMM, C = A * Bt^T (r8 structure, unchanged) --------
template <int BM, int EPI>
__global__ __launch_bounds__(512, 4) void gemmf8(const char* __restrict__ A8,
                                                 const char* __restrict__ B8,
                                                 void* __restrict__ Cout,
                                                 const float* __restrict__ resid,
                                                 int Ndim, int Kdim, int ntiles,
                                                 int coff, float scl) {
  constexpr int MF = BM / 32;
  constexpr int ASZ = BM * 64;
  constexpr int BSZ = 256 * 64;
  __shared__ alignas(16) char As[2 * ASZ];
  __shared__ alignas(16) char Bs[2 * BSZ];

  const int tid = threadIdx.x;
  const int lane = tid & 63;
  const int w = tid >> 6;
  const int wm = w >> 2, wn = w & 3;

  const int qq = gridDim.x >> 3;
  const int wgid = (blockIdx.x & 7) * qq + (blockIdx.x >> 3);
  const int m0 = (wgid / ntiles) * BM;
  const int n0 = (wgid % ntiles) * 256;

  f32x4 acc[MF][4] = {};

  const int rowS = (tid >> 2) & 127;
  const int uS = tid & 3;
  const int luS = uS ^ ((rowS >> 1) & 3);
  const char* gA = A8 + (size_t)(m0 + rowS) * Kdim + luS * 16;
  const char* gB = B8 + (size_t)(n0 + rowS) * Kdim + luS * 16;
  char* lA = (char*)As;
  char* lB = (char*)Bs;

  const int lr = lane & 15;
  const int hi = lane >> 4;
  const int sw = (lr >> 1) & 3;
  const int kof0 = ((((hi >> 1)) ^ sw) << 4) + (hi & 1) * 8;
  const int kof1 = (((2 + (hi >> 1)) ^ sw) << 4) + (hi & 1) * 8;
  const int rowA = (wm * (BM / 2) + lr) * 64;
  const int rowB = (wn * 64 + lr) * 64;
  const int NT = Kdim >> 6;

  if constexpr (BM == 128) {
    async16(gA, lA + tid * 16);
  } else {
    if (tid < 256) async16(gA, lA + tid * 16);
  }
  async16(gB, lB + tid * 16);
  async16(gB + (size_t)128 * Kdim, lB + 8192 + tid * 16);
  S_VM0();
  S_BAR();

  for (int t = 0; t < NT; ++t) {
    const int buf = t & 1;
    const char* pA = lA + buf * ASZ + rowA;
    const char* pB = lB + buf * BSZ + rowB;

    long a0[MF], b0[4], a1[MF], b1[4];
    #pragma unroll
    for (int ni = 0; ni < 4; ++ni) b0[ni] = *(const long*)(pB + ni * 1024 + kof0);
    #pragma unroll
    for (int mi = 0; mi < MF; ++mi) a0[mi] = *(const long*)(pA + mi * 1024 + kof0);
    SCHED_PIN();
    #pragma unroll
    for (int ni = 0; ni < 4; ++ni) b1[ni] = *(const long*)(pB + ni * 1024 + kof1);
    #pragma unroll
    for (int mi = 0; mi < MF; ++mi) a1[mi] = *(const long*)(pA + mi * 1024 + kof1);
    SCHED_PIN();
    if (t + 1 < NT) {
      const char* gAt = gA + (size_t)(t + 1) * 64;
      const char* gBt = gB + (size_t)(t + 1) * 64;
      char* lAd = lA + (buf ^ 1) * ASZ + tid * 16;
      char* lBd = lB + (buf ^ 1) * BSZ + tid * 16;
      if constexpr (BM == 128) {
        async16(gAt, lAd);
      } else {
        if (tid < 256) async16(gAt, lAd);
      }
      async16(gBt, lBd);
      async16(gBt + (size_t)128 * Kdim, lBd + 8192);
    }
    SCHED_PIN();
    __builtin_amdgcn_s_setprio(1);
    #pragma unroll
    for (int mi = 0; mi < MF; ++mi)
      #pragma unroll
      for (int ni = 0; ni < 4; ++ni)
        acc[mi][ni] = __builtin_amdgcn_mfma_f32_16x16x32_fp8_fp8(a0[mi], b0[ni], acc[mi][ni], 0, 0, 0);
    __builtin_amdgcn_s_setprio(0);
    SCHED_PIN();
    __builtin_amdgcn_s_setprio(1);
    #pragma unroll
    for (int mi = 0; mi < MF; ++mi)
      #pragma unroll
      for (int ni = 0; ni < 4; ++ni)
        acc[mi][ni] = __builtin_amdgcn_mfma_f32_16x16x32_fp8_fp8(a1[mi], b1[ni], acc[mi][ni], 0, 0, 0);
    __builtin_amdgcn_s_setprio(0);
    SCHED_PIN();
    if (t + 1 < NT) S_VM0();
    S_BAR();
  }

  #pragma unroll
  for (int mi = 0; mi < MF; ++mi) {
    const int rbase = m0 + wm * (BM / 2) + mi * 16 + ((lane >> 4) << 2);
    #pragma unroll
    for (int ni = 0; ni < 4; ++ni) {
      const int col = coff + n0 + wn * 64 + ni * 16 + (lane & 15);
      #pragma unroll
      for (int r = 0; r < 4; ++r) {
        const size_t off = (size_t)(rbase + r) * Ndim + col;
        if constexpr (EPI == 0) ((__bf16*)Cout)[off] = (__bf16)(acc[mi][ni][r] * scl);
        else                    ((float*)Cout)[off] = resid[off] + acc[mi][ni][r] * scl;
      }
    }
  }
}

// ---------------- GEGLU gl-half: fp8 into fused8 cols [0,1024) ----------------
__global__ __launch_bounds__(256) void geglu_gl(const __bf16* __restrict__ h,
                                                char* __restrict__ fused8) {
  const int idx = blockIdx.x * 256 + threadIdx.x;   // 8192 rows x 128 chunks
  const int row = idx >> 7;
  const int col = (idx & 127) * 8;
  const bf16x8 lin = *(const bf16x8*)&h[(size_t)row * NEXP + 256 + col];
  const bf16x8 pre = *(const bf16x8*)&h[(size_t)row * NEXP + 2304 + col];
  float g[8];
  #pragma unroll
  for (int j = 0; j < 8; ++j) {
    const float p = (float)pre[j];
    const float gg = 0.5f * p * (1.0f + erff(p * 0.70710678118f));
    g[j] = (float)lin[j] * gg;
  }
  u32* dst = (u32*)&fused8[(size_t)row * EDIM + col];
  dst[0] = pack4_e4m3(g[0], g[1], g[2], g[3]);
  dst[1] = pack4_e4m3(g[4], g[5], g[6], g[7]);
}

// --------- GEGLU v-half -> transposed fp8 V: vTb[b][h][sblk16][d256][s64] ------
__global__ __launch_bounds__(256) void geglu_vT(const __bf16* __restrict__ h,
                                                char* __restrict__ vTb) {
  const int blk = blockIdx.x;          // 8*4*16 = 512
  const int sblk = blk & 15;
  const int head = (blk >> 4) & 3;
  const int b = blk >> 6;
  const int t = threadIdx.x;
  __shared__ u32 vt[64][66];           // [s][256 bytes as u32 + 2 pad]

  // compute: thread (s_l = t>>2, qq = t&3); d = j*32 + qq*8
  const int s_l = t >> 2, qq = t & 3;
  const size_t rowh = (size_t)(b * 1024 + sblk * 64 + s_l) * NEXP;
  #pragma unroll
  for (int j = 0; j < 8; ++j) {
    const int d = j * 32 + qq * 8;
    const bf16x8 lin = *(const bf16x8*)&h[rowh + 1280 + head * 256 + d];
    const bf16x8 pre = *(const bf16x8*)&h[rowh + 3328 + head * 256 + d];
    float g[8];
    #pragma unroll
    for (int i = 0; i < 8; ++i) {
      const float p = (float)pre[i];
      const float gg = 0.5f * p * (1.0f + erff(p * 0.70710678118f));
      g[i] = (float)lin[i] * gg;
    }
    vt[s_l][(d >> 2)] = pack4_e4m3(g[0], g[1], g[2], g[3]);
    vt[s_l][(d >> 2) + 1] = pack4_e4m3(g[4], g[5], g[6], g[7]);
  }
  __syncthreads();
  // write: thread t = d; gather 64 s-bytes (byte d of each row) -> 16 u32
  const int d = t;
  const int wsel = (d & 3) * 8;
  char* dst = vTb + (((size_t)(b * 4 + head) * 16 + sblk) * 256 + d) * 64;
  #pragma unroll
  for (int c = 0; c < 4; ++c) {
    u32 wo[4];
    #pragma unroll
    for (int k = 0; k < 4; ++k) {
      const int s0 = c * 16 + k * 4;
      const u32 r0 = vt[s0 + 0][d >> 2];
      const u32 r1 = vt[s0 + 1][d >> 2];
      const u32 r2 = vt[s0 + 2][d >> 2];
      const u32 r3 = vt[s0 + 3][d >> 2];
      wo[k] = ((r0 >> wsel) & 0xffu) | (((r1 >> wsel) & 0xffu) << 8) |
              (((r2 >> wsel) & 0xffu) << 16) | (((r3 >> wsel) & 0xffu) << 24);
    }
    *(uint4*)(dst + c * 16) = make_uint4(wo[0], wo[1], wo[2], wo[3]);
  }
}

// ------------- MFMA sliding-window attention (W=32) -------------
// block = (b, head, 128-q tile); 4 waves x 32 queries.
// S^T = mfma_bf16(A=K, B=Q^T)  (operands read directly from h)
// O^T = mfma_fp8(A=V^T (LDS), B=P (LDS))  -> 4 regs = 4 consecutive dims -> u32 store
__global__ __launch_bounds__(256, 2) void attn_mfma(const __bf16* __restrict__ h,
                                                    const char* __restrict__ vTb,
                                                    char* __restrict__ fused8,
                                                    const float* __restrict__ pbm) {
  const int blk = blockIdx.x;          // 8*4*8 = 256
  const int qblk = blk & 7;
  const int head = (blk >> 3) & 3;
  const int b = blk >> 5;
  const int tid = threadIdx.x;
  const int lane = tid & 63;
  const int w = tid >> 6;
  __shared__ char vt[256 * 176];       // V^T window: [d 256][key 160 + 16 pad] fp8
  __shared__ char pl[4][32 * 80];      // per-wave P: [q 32][key 64 + 16 pad] fp8

  const float p = pbm[0];
  const float sp = (p > 20.0f) ? p : log1pf(expf(p));

  // ---- stage V^T window: keys [qblk*128-32, +160) ; obeys base+lane*16 rule ----
  {
    const int m = qblk * 2;
    const char* base = vTb + ((size_t)(b * 4 + head) * 16) * 16384;
    #pragma unroll
    for (int it = 0; it < 11; ++it) {
      const int U = it * 256 + tid;          // flat 16B-unit index into vt
      const int d = U / 11;
      const int slot = U - d * 11;           // 0..10 (slot 10 = pad)
      int sb, so;
      if (slot >= 10)      { sb = m; so = 0; }
      else if (slot < 2)   { sb = m - 1; so = 32 + slot * 16; }
      else if (slot < 6)   { sb = m; so = (slot - 2) * 16; }
      else                 { sb = m + 1; so = (slot - 6) * 16; }
      if (sb < 0) sb = 0;                    // qblk 0: garbage, masked by scores
      async16(base + ((size_t)sb * 256 + d) * 64 + so, vt + U * 16);
    }
  }

  const int col = lane & 15;
  const int hi = lane >> 4;
  const int qb = qblk * 128 + w * 32;        // wave's query base (abs in S)
  const int kb = qb - 32;                    // wave's key base (abs)

  // ---- scores: S^T(64k x 32q) = K . Q^T, bf16 MFMA, operands from global ----
  f32x4 sc[4][2] = {};
  bf16x8 afr[4], bfr[2];
  #pragma unroll
  for (int mf = 0; mf < 4; ++mf) {
    int key = kb + mf * 16 + col;
    if (key < 0) key = 0;
    afr[mf] = *(const bf16x8*)&h[(size_t)(b * 1024 + key) * NEXP + 128 + head * 32 + hi * 8];
  }
  #pragma unroll
  for (int nf = 0; nf < 2; ++nf)
    bfr[nf] = *(const bf16x8*)&h[(size_t)(b * 1024 + qb + nf * 16 + col) * NEXP + head * 32 + hi * 8];
  #pragma unroll
  for (int mf = 0; mf < 4; ++mf)
    #pragma unroll
    for (int nf = 0; nf < 2; ++nf)
      sc[mf][nf] = __builtin_amdgcn_mfma_f32_16x16x32_bf16(afr[mf], bfr[nf], sc[mf][nf], 0, 0, 0);

  // ---- bias + causal/window mask + softmax (per q-column) ----
  // element (mf,nf,r): key = kb + mf*16 + hi*4 + r ; q = qb + nf*16 + col
  #pragma unroll
  for (int nf = 0; nf < 2; ++nf) {
    #pragma unroll
    for (int mf = 0; mf < 4; ++mf)
      #pragma unroll
      for (int r = 0; r < 4; ++r) {
        const int delta = mf * 16 + hi * 4 + r - nf * 16 - col - 32;
        const int keyabs = kb + mf * 16 + hi * 4 + r;
        const bool valid = (delta <= 0) & (delta >= -31) & (keyabs >= 0);
        sc[mf][nf][r] = valid ? sc[mf][nf][r] * 0.1767766953f + sp * (float)delta : -1e30f;
      }
    float m = -1e30f;
    #pragma unroll
    for (int mf = 0; mf < 4; ++mf)
      #pragma unroll
      for (int r = 0; r < 4; ++r) m = fmaxf(m, sc[mf][nf][r]);
    m = fmaxf(m, __shfl_xor(m, 16));
    m = fmaxf(m, __shfl_xor(m, 32));
    float s = 0.0f;
    #pragma unroll
    for (int mf = 0; mf < 4; ++mf)
      #pragma unroll
      for (int r = 0; r < 4; ++r) {
        const float e = __expf(sc[mf][nf][r] - m);
        sc[mf][nf][r] = e;
        s += e;
      }
    s += __shfl_xor(s, 16);
    s += __shfl_xor(s, 32);
    const float inv = 1.0f / s;
    #pragma unroll
    for (int mf = 0; mf < 4; ++mf) {
      const u32 pk = pack4_e4m3(sc[mf][nf][0] * inv, sc[mf][nf][1] * inv,
                                sc[mf][nf][2] * inv, sc[mf][nf][3] * inv);
      *(u32*)&pl[w][(nf * 16 + col) * 80 + mf * 16 + hi * 4] = pk;
    }
  }

  __syncthreads();   // V^T DMA landed (vmcnt drained per-wave) + P writes visible

  // ---- PV: O^T(256d x 32q) = V^T . P^T, fp8 MFMA, K=64 keys (2 kf) ----
  const char* ppl = pl[w];
  const int kloc = w * 32;                   // wave window start within vt keys
  f32x4 ao[16][2] = {};
  #pragma unroll
  for (int kf = 0; kf < 2; ++kf) {
    long bfrag[2];
    #pragma unroll
    for (int nf = 0; nf < 2; ++nf)
      bfrag[nf] = *(const long*)&ppl[(nf * 16 + col) * 80 + kf * 32 + hi * 8];
    #pragma unroll
    for (int mf = 0; mf < 16; ++mf) {
      const long af = *(const long*)&vt[(mf * 16 + col) * 176 + kloc + kf * 32 + hi * 8];
      #pragma unroll
      for (int nf = 0; nf < 2; ++nf)
        ao[mf][nf] = __builtin_amdgcn_mfma_f32_16x16x32_fp8_fp8(af, bfrag[nf], ao[mf][nf], 0, 0, 0);
    }
  }

  // ---- store O^T: 4 regs = 4 consecutive dims -> one u32 per frag ----
  #pragma unroll
  for (int mf = 0; mf < 16; ++mf)
    #pragma unroll
    for (int nf = 0; nf < 2; ++nf) {
      const u32 pk = pack4_e4m3(ao[mf][nf][0], ao[mf][nf][1], ao[mf][nf][2], ao[mf][nf][3]);
      *(u32*)&fused8[(size_t)(b * 1024 + qb + nf * 16 + col) * EDIM + 1024 +
                     head * 256 + mf * 16 + hi * 4] = pk;
    }
}

// ---------------- host launch ----------------
extern "C" void kernel_launch(void* const* d_in, const int* in_sizes, int n_in,
                              void* d_out, int out_size, void* d_ws, size_t ws_size,
                              hipStream_t stream) {
  const float* x = (const float*)d_in[0];
  const float* norm_w = (const float*)d_in[2];
  const float* expand_w = (const float*)d_in[3];
  const float* project_w = (const float*)d_in[4];
  const float* pbm = (const float*)d_in[5];
  float* out = (float*)d_out;

  char* ws = (char*)d_ws;
  __bf16* xn    = (__bf16*)(ws);                  // 16,777,216
  u32*    xn8   = (u32*)(ws + 16777216);          //  8,388,608
  __bf16* wqk   = (__bf16*)(ws + 25165824);       //    524,288
  char*   wexp8 = (char*)(ws + 25690112);         //  4,194,304 (x16)
  char*   wproj8= (char*)(ws + 29884416);         //  2,097,152 (x256)
  __bf16* h     = (__bf16*)(ws + 31981568);       // 71,303,168
  char*   fused8= (char*)(ws + 103284736);        // 16,777,216
  char*   vTb   = (char*)(ws + 120061952);        //  8,388,608
  // total 128,450,560 bytes

  ln_kernel<<<MROWS, 256, 0, stream>>>(x, norm_w, xn, xn8);
  cast_kernel<<<256, 256, 0, stream>>>(expand_w, wqk, 65536);
  cast8_kernel<<<4096, 256, 0, stream>>>(expand_w + 256 * DDIM, (u32*)wexp8, 1048576, 16.0f);
  cast8_kernel<<<2048, 256, 0, stream>>>(project_w, (u32*)wproj8, 524288, 256.0f);
  // q/k columns: M=8192, N=256, K=1024 (bf16)
  gemm_bt<<<dim3(64, 2), 256, 0, stream>>>(xn, wqk, h, NEXP, DDIM, 0);
  // lin|pre columns: M=8192, N=4096, K=1024 fp8 -> 1024 blocks
  gemmf8<128, 0><<<1024, 512, 0, stream>>>((const char*)xn8, wexp8, (void*)h, nullptr,
                                           NEXP, DDIM, 16, 256, 1.0f / 16.0f);
  geglu_gl<<<4096, 256, 0, stream>>>(h, fused8);
  geglu_vT<<<512, 256, 0, stream>>>(h, vTb);
  attn_mfma<<<256, 256, 0, stream>>>(h, vTb, fused8, pbm);
  // project: M=8192, N=1024, K=2048 fp8 -> 512 blocks
  gemmf8<64, 1><<<512, 512, 0, stream>>>(fused8, wproj8, (void*)out, x,
                                         DDIM, EDIM, 4, 0, 1.0f / 256.0f);
}

// Round 10
// 152.215 us; speedup vs baseline: 1.6387x; 1.1319x over previous
//
#include <hip/hip_runtime.h>
#include <hip/hip_bf16.h>
#include <hip/hip_fp8.h>

typedef __bf16 bf16x8 __attribute__((ext_vector_type(8)));
typedef __bf16 bf16x4 __attribute__((ext_vector_type(4)));
typedef float f32x4 __attribute__((ext_vector_type(4)));
typedef unsigned int u32;
typedef __attribute__((address_space(3))) u32 lds_u32_t;
typedef __attribute__((address_space(1))) u32 glb_u32_t;

#define MROWS 8192      // B*S
#define DDIM 1024
#define EDIM 2048
#define HQK 256         // h buffer now holds only q|k columns

#define S_BAR() asm volatile("s_barrier" ::: "memory")
#define S_VM0() asm volatile("s_waitcnt vmcnt(0)" ::: "memory")
#define SCHED_PIN() __builtin_amdgcn_sched_barrier(0)

__device__ __forceinline__ void async16(const void* g, void* l) {
  __builtin_amdgcn_global_load_lds((const glb_u32_t*)g, (lds_u32_t*)l, 16, 0, 0);
}

__device__ __forceinline__ u32 pack4_e4m3(float f0, float f1, float f2, float f3) {
  __hip_fp8_e4m3 a(f0), b(f1), c(f2), d(f3);
  return (u32)a.__x | ((u32)b.__x << 8) | ((u32)c.__x << 16) | ((u32)d.__x << 24);
}

// ---------------- LayerNorm + bf16 cast + fp8 cast ----------------
__global__ __launch_bounds__(256) void ln_kernel(const float* __restrict__ x,
                                                 const float* __restrict__ wgt,
                                                 __bf16* __restrict__ xn,
                                                 u32* __restrict__ xn8) {
  const int row = blockIdx.x;
  const int t = threadIdx.x;
  const float4 v = ((const float4*)(x + (size_t)row * DDIM))[t];
  float s = v.x + v.y + v.z + v.w;
  float ss = v.x * v.x + v.y * v.y + v.z * v.z + v.w * v.w;
  #pragma unroll
  for (int o = 32; o > 0; o >>= 1) {
    s += __shfl_down(s, o);
    ss += __shfl_down(ss, o);
  }
  __shared__ float red[8];
  const int lane = t & 63, wv = t >> 6;
  if (lane == 0) { red[wv] = s; red[4 + wv] = ss; }
  __syncthreads();
  s = red[0] + red[1] + red[2] + red[3];
  ss = red[4] + red[5] + red[6] + red[7];
  const float mu = s * (1.0f / 1024.0f);
  const float rstd = rsqrtf(ss * (1.0f / 1024.0f) - mu * mu + 1e-5f);
  const float4 w4 = ((const float4*)wgt)[t];
  const float f0 = (v.x - mu) * rstd * w4.x;
  const float f1 = (v.y - mu) * rstd * w4.y;
  const float f2 = (v.z - mu) * rstd * w4.z;
  const float f3 = (v.w - mu) * rstd * w4.w;
  bf16x4 o;
  o[0] = (__bf16)f0; o[1] = (__bf16)f1; o[2] = (__bf16)f2; o[3] = (__bf16)f3;
  ((bf16x4*)(xn + (size_t)row * DDIM))[t] = o;
  xn8[row * 256 + t] = pack4_e4m3(f0, f1, f2, f3);
}

// ---------------- fp32 -> bf16 weight cast ----------------
__global__ __launch_bounds__(256) void cast_kernel(const float* __restrict__ src,
                                                   __bf16* __restrict__ dst, int n4) {
  const int i = blockIdx.x * 256 + threadIdx.x;
  if (i < n4) {
    const float4 v = ((const float4*)src)[i];
    bf16x4 o;
    o[0] = (__bf16)v.x; o[1] = (__bf16)v.y; o[2] = (__bf16)v.z; o[3] = (__bf16)v.w;
    ((bf16x4*)dst)[i] = o;
  }
}

// ---------------- fp32 -> fp8 weight cast (pre-scaled) ----------------
__global__ __launch_bounds__(256) void cast8_kernel(const float* __restrict__ src,
                                                    u32* __restrict__ dst, int n4, float scale) {
  const int i = blockIdx.x * 256 + threadIdx.x;
  if (i < n4) {
    const float4 v = ((const float4*)src)[i];
    dst[i] = pack4_e4m3(v.x * scale, v.y * scale, v.z * scale, v.w * scale);
  }
}

// ------ fp32 -> fp8 interleaved expand-weight cast (lin/pre frag pairs) ------
// src = expand_w + 256*1024 (rows: 2048 lin then 2048 pre).
// dst row r' = (c>>4)*32 + pre*16 + (c&15) for output col c in [0,2048).
__global__ __launch_bounds__(256) void cast8i_kernel(const float* __restrict__ src,
                                                     u32* __restrict__ dst) {
  const int i = blockIdx.x * 256 + threadIdx.x;   // 4096*256
  const int rp = i >> 8, k4 = i & 255;
  const int c = ((rp >> 5) << 4) | (rp & 15);
  const int pre = (rp >> 4) & 1;
  const float4 v = *(const float4*)(src + ((size_t)(pre * 2048 + c)) * 1024 + k4 * 4);
  dst[i] = pack4_e4m3(v.x * 16.0f, v.y * 16.0f, v.z * 16.0f, v.w * 16.0f);
}

// ------------- small m97-style bf16 GEMM (skinny q/k columns) -------------
__global__ __launch_bounds__(256) void gemm_bt(const __bf16* __restrict__ A,
                                               const __bf16* __restrict__ Bt,
                                               __bf16* __restrict__ Cout,
                                               int Ndim, int Kdim, int coff) {
  __shared__ __bf16 As[128 * 32];
  __shared__ __bf16 Bs[128 * 32];
  const int t = threadIdx.x;
  const int lane = t & 63;
  const int w = t >> 6;
  const int wm = w >> 1, wn = w & 1;
  const int m0 = blockIdx.x * 128;
  const int n0 = blockIdx.y * 128;

  f32x4 acc[4][4] = {};

  const int cA = w * 2;
  const int sr = cA * 16 + (lane >> 2);
  const int sc = (lane & 3) * 8;
  const __bf16* gA0 = A + (size_t)(m0 + sr) * Kdim + sc;
  const __bf16* gA1 = A + (size_t)(m0 + sr + 16) * Kdim + sc;
  const __bf16* gB0 = Bt + (size_t)(n0 + sr) * Kdim + sc;
  const __bf16* gB1 = Bt + (size_t)(n0 + sr + 16) * Kdim + sc;
  __bf16* lA0 = As + cA * 512;
  __bf16* lA1 = As + (cA + 1) * 512;
  __bf16* lB0 = Bs + cA * 512;
  __bf16* lB1 = Bs + (cA + 1) * 512;

  const int lr = lane & 15;
  const int lk = (lane >> 4) * 8;
  const int nk = Kdim >> 5;

  for (int kt = 0; kt < nk; ++kt) {
    __syncthreads();
    const int ko = kt * 32;
    async16(gA0 + ko, lA0);
    async16(gA1 + ko, lA1);
    async16(gB0 + ko, lB0);
    async16(gB1 + ko, lB1);
    __syncthreads();
    bf16x8 a[4], b[4];
    #pragma unroll
    for (int i = 0; i < 4; ++i)
      a[i] = *(const bf16x8*)&As[(wm * 64 + i * 16 + lr) * 32 + lk];
    #pragma unroll
    for (int i = 0; i < 4; ++i)
      b[i] = *(const bf16x8*)&Bs[(wn * 64 + i * 16 + lr) * 32 + lk];
    #pragma unroll
    for (int i = 0; i < 4; ++i)
      #pragma unroll
      for (int j = 0; j < 4; ++j)
        acc[i][j] = __builtin_amdgcn_mfma_f32_16x16x32_bf16(a[i], b[j], acc[i][j], 0, 0, 0);
  }

  #pragma unroll
  for (int i = 0; i < 4; ++i) {
    const int rbase = m0 + wm * 64 + i * 16 + ((lane >> 4) << 2);
    #pragma unroll
    for (int j = 0; j < 4; ++j) {
      const int col = coff + n0 + wn * 64 + j * 16 + (lane & 15);
      #pragma unroll
      for (int r = 0; r < 4; ++r)
        Cout[(size_t)(rbase + r) * Ndim + col] = (__bf16)acc[i][j][r];
    }
  }
}

// ------- fp8 GEMM + fused GEGLU epilogue (expand / lin|pre columns) -------
// BM=128, BN=256 (interleaved lin/pre frags), BK=64. acc[mi][2p]=lin,
// acc[mi][2p+1]=pre -> g = lin*gelu(pre) in fp32 -> fp8 byte store.
__global__ __launch_bounds__(512, 4) void gemm1glu(const char* __restrict__ A8,
                                                   const char* __restrict__ B8,
                                                   char* __restrict__ fused8,
                                                   char* __restrict__ vbuf8) {
  constexpr int ASZ = 128 * 64;
  constexpr int BSZ = 256 * 64;
  constexpr int Kdim = 1024;
  __shared__ alignas(16) char As[2 * ASZ];
  __shared__ alignas(16) char Bs[2 * BSZ];

  const int tid = threadIdx.x;
  const int lane = tid & 63;
  const int w = tid >> 6;
  const int wm = w >> 2, wn = w & 3;

  const int qq = gridDim.x >> 3;
  const int wgid = (blockIdx.x & 7) * qq + (blockIdx.x >> 3);
  const int m0 = (wgid / 16) * 128;
  const int nblk = wgid % 16;
  const int n0r = nblk * 256;          // weight-row base

  f32x4 acc[4][4] = {};

  const int rowS = (tid >> 2) & 127;
  const int uS = tid & 3;
  const int luS = uS ^ ((rowS >> 1) & 3);
  const char* gA = A8 + (size_t)(m0 + rowS) * Kdim + luS * 16;
  const char* gB = B8 + (size_t)(n0r + rowS) * Kdim + luS * 16;
  char* lA = (char*)As;
  char* lB = (char*)Bs;

  const int lr = lane & 15;
  const int hi = lane >> 4;
  const int sw = (lr >> 1) & 3;
  const int kof0 = ((((hi >> 1)) ^ sw) << 4) + (hi & 1) * 8;
  const int kof1 = (((2 + (hi >> 1)) ^ sw) << 4) + (hi & 1) * 8;
  const int rowA = (wm * 64 + lr) * 64;
  const int rowB = (wn * 64 + lr) * 64;
  const int NT = Kdim >> 6;

  async16(gA, lA + tid * 16);
  async16(gB, lB + tid * 16);
  async16(gB + (size_t)128 * Kdim, lB + 8192 + tid * 16);
  S_VM0();
  S_BAR();

  for (int t = 0; t < NT; ++t) {
    const int buf = t & 1;
    const char* pA = lA + buf * ASZ + rowA;
    const char* pB = lB + buf * BSZ + rowB;

    long a0[4], b0[4], a1[4], b1[4];
    #pragma unroll
    for (int ni = 0; ni < 4; ++ni) b0[ni] = *(const long*)(pB + ni * 1024 + kof0);
    #pragma unroll
    for (int mi = 0; mi < 4; ++mi) a0[mi] = *(const long*)(pA + mi * 1024 + kof0);
    SCHED_PIN();
    #pragma unroll
    for (int ni = 0; ni < 4; ++ni) b1[ni] = *(const long*)(pB + ni * 1024 + kof1);
    #pragma unroll
    for (int mi = 0; mi < 4; ++mi) a1[mi] = *(const long*)(pA + mi * 1024 + kof1);
    SCHED_PIN();
    if (t + 1 < NT) {
      const char* gAt = gA + (size_t)(t + 1) * 64;
      const char* gBt = gB + (size_t)(t + 1) * 64;
      char* lAd = lA + (buf ^ 1) * ASZ + tid * 16;
      char* lBd = lB + (buf ^ 1) * BSZ + tid * 16;
      async16(gAt, lAd);
      async16(gBt, lBd);
      async16(gBt + (size_t)128 * Kdim, lBd + 8192);
    }
    SCHED_PIN();
    __builtin_amdgcn_s_setprio(1);
    #pragma unroll
    for (int mi = 0; mi < 4; ++mi)
      #pragma unroll
      for (int ni = 0; ni < 4; ++ni)
        acc[mi][ni] = __builtin_amdgcn_mfma_f32_16x16x32_fp8_fp8(a0[mi], b0[ni], acc[mi][ni], 0, 0, 0);
    __builtin_amdgcn_s_setprio(0);
    SCHED_PIN();
    __builtin_amdgcn_s_setprio(1);
    #pragma unroll
    for (int mi = 0; mi < 4; ++mi)
      #pragma unroll
      for (int ni = 0; ni < 4; ++ni)
        acc[mi][ni] = __builtin_amdgcn_mfma_f32_16x16x32_fp8_fp8(a1[mi], b1[ni], acc[mi][ni], 0, 0, 0);
    __builtin_amdgcn_s_setprio(0);
    SCHED_PIN();
    if (t + 1 < NT) S_VM0();
    S_BAR();
  }

  // fused GEGLU epilogue. col c = nblk*128 + wn*32 + p*16 + (lane&15)
  const int col = lane & 15;
  const int cbase = nblk * 128 + wn * 32;
  const bool isv = nblk >= 8;
  #pragma unroll
  for (int mi = 0; mi < 4; ++mi) {
    const int rbase = m0 + wm * 64 + mi * 16 + (hi << 2);
    #pragma unroll
    for (int p = 0; p < 2; ++p) {
      const int c = cbase + p * 16 + col;
      #pragma unroll
      for (int r = 0; r < 4; ++r) {
        const float l = acc[mi][2 * p][r] * 0.0625f;
        const float q = acc[mi][2 * p + 1][r] * 0.0625f;
        const float g = l * 0.5f * q * (1.0f + erff(q * 0.70710678118f));
        __hip_fp8_e4m3 f8(g);
        if (isv) vbuf8[(size_t)(rbase + r) * 1024 + (c - 1024)] = (char)f8.__x;
        else     fused8[(size_t)(rbase + r) * EDIM + c] = (char)f8.__x;
      }
    }
  }
}

// ---------------- fp8 project GEMM, BK=128, 8-unit XOR swizzle ----------------
// BM=64, BN=256, BK=128B rows. out = resid + acc*scl (fp32).
__global__ __launch_bounds__(512, 2) void gemmproj(const char* __restrict__ A8,
                                                   const char* __restrict__ B8,
                                                   float* __restrict__ out,
                                                   const float* __restrict__ resid,
                                                   float scl) {
  constexpr int ASZ = 64 * 128;    // 8KB
  constexpr int BSZ = 256 * 128;   // 32KB
  constexpr int Kdim = 2048;
  __shared__ alignas(16) char As[2 * ASZ];
  __shared__ alignas(16) char Bs[2 * BSZ];

  const int tid = threadIdx.x;
  const int lane = tid & 63;
  const int w = tid >> 6;
  const int wm = w >> 2, wn = w & 3;

  const int qq = gridDim.x >> 3;
  const int wgid = (blockIdx.x & 7) * qq + (blockIdx.x >> 3);
  const int m0 = (wgid / 4) * 64;
  const int n0 = (wgid % 4) * 256;

  f32x4 acc[2][4] = {};

  const int rowS = tid >> 3;           // 0..63
  const int uS = tid & 7;
  const int luS = uS ^ (rowS & 7);
  const char* gA = A8 + (size_t)(m0 + rowS) * Kdim + luS * 16;
  const char* gB = B8 + (size_t)(n0 + rowS) * Kdim + luS * 16;
  char* lA = (char*)As;
  char* lB = (char*)Bs;

  const int lr = lane & 15;
  const int hi = lane >> 4;
  int kof[4];
  #pragma unroll
  for (int kq = 0; kq < 4; ++kq)
    kof[kq] = (((kq * 2 + (hi >> 1)) ^ (lr & 7)) << 4) + (hi & 1) * 8;
  const int rowA = (wm * 32 + lr) * 128;
  const int rowB = (wn * 64 + lr) * 128;
  const int NT = Kdim >> 7;            // 16

  // prologue: stage tile 0
  async16(gA, lA + tid * 16);
  #pragma unroll
  for (int c = 0; c < 4; ++c) async16(gB + (size_t)c * 64 * Kdim, lB + c * 8192 + tid * 16);
  S_VM0();
  S_BAR();

  for (int t = 0; t < NT; ++t) {
    const int buf = t & 1;
    const char* pA = lA + buf * ASZ + rowA;
    const char* pB = lB + buf * BSZ + rowB;

    long a[4][2], bb[4][4];
    #pragma unroll
    for (int kq = 0; kq < 4; ++kq) {
      #pragma unroll
      for (int ni = 0; ni < 4; ++ni) bb[kq][ni] = *(const long*)(pB + ni * 2048 + kof[kq]);
      #pragma unroll
      for (int mi = 0; mi < 2; ++mi) a[kq][mi] = *(const long*)(pA + mi * 2048 + kof[kq]);
    }
    SCHED_PIN();
    if (t + 1 < NT) {
      const char* gAt = gA + (size_t)(t + 1) * 128;
      const char* gBt = gB + (size_t)(t + 1) * 128;
      char* lAd = lA + (buf ^ 1) * ASZ + tid * 16;
      char* lBd = lB + (buf ^ 1) * BSZ + tid * 16;
      async16(gAt, lAd);
      #pragma unroll
      for (int c = 0; c < 4; ++c) async16(gBt + (size_t)c * 64 * Kdim, lBd + c * 8192);
    }
    SCHED_PIN();
    #pragma unroll
    for (int kq = 0; kq < 4; ++kq) {
      __builtin_amdgcn_s_setprio(1);
      #pragma unroll
      for (int mi = 0; mi < 2; ++mi)
        #pragma unroll
        for (int ni = 0; ni < 4; ++ni)
          acc[mi][ni] = __builtin_amdgcn_mfma_f32_16x16x32_fp8_fp8(a[kq][mi], bb[kq][ni], acc[mi][ni], 0, 0, 0);
      __builtin_amdgcn_s_setprio(0);
      SCHED_PIN();
    }
    if (t + 1 < NT) S_VM0();
    S_BAR();
  }

  #pragma unroll
  for (int mi = 0; mi < 2; ++mi) {
    const int rbase = m0 + wm * 32 + mi * 16 + (hi << 2);
    #pragma unroll
    for (int ni = 0; ni < 4; ++ni) {
      const int col = n0 + wn * 64 + ni * 16 + (lane & 15);
      #pragma unroll
      for (int r = 0; r < 4; ++r) {
        const size_t off = (size_t)(rbase + r) * DDIM + col;
        out[off] = resid[off] + acc[mi][ni][r] * scl;
      }
    }
  }
}

// --------- fp8 V transpose: vbuf8[8192][1024] -> vTb[b][h][sblk16][d256][s64] ------
__global__ __launch_bounds__(256) void vT8_kernel(const char* __restrict__ vbuf8,
                                                  char* __restrict__ vTb) {
  const int blk = blockIdx.x;          // 512
  const int sblk = blk & 15;
  const int head = (blk >> 4) & 3;
  const int b = blk >> 6;
  const int t = threadIdx.x;
  __shared__ u32 vt[64][66];

  const int s_l = t >> 2, q4 = t & 3;
  const uint4* src = (const uint4*)&vbuf8[(size_t)(b * 1024 + sblk * 64 + s_l) * 1024 +
                                          head * 256 + q4 * 64];
  #pragma unroll
  for (int c = 0; c < 4; ++c) {
    const uint4 ww = src[c];
    vt[s_l][q4 * 16 + c * 4 + 0] = ww.x;
    vt[s_l][q4 * 16 + c * 4 + 1] = ww.y;
    vt[s_l][q4 * 16 + c * 4 + 2] = ww.z;
    vt[s_l][q4 * 16 + c * 4 + 3] = ww.w;
  }
  __syncthreads();
  const int d = t;
  const int wsel = (d & 3) * 8;
  char* dst = vTb + (((size_t)(b * 4 + head) * 16 + sblk) * 256 + d) * 64;
  #pragma unroll
  for (int c = 0; c < 4; ++c) {
    u32 wo[4];
    #pragma unroll
    for (int k = 0; k < 4; ++k) {
      const int s0 = c * 16 + k * 4;
      const u32 r0 = vt[s0 + 0][d >> 2];
      const u32 r1 = vt[s0 + 1][d >> 2];
      const u32 r2 = vt[s0 + 2][d >> 2];
      const u32 r3 = vt[s0 + 3][d >> 2];
      wo[k] = ((r0 >> wsel) & 0xffu) | (((r1 >> wsel) & 0xffu) << 8) |
              (((r2 >> wsel) & 0xffu) << 16) | (((r3 >> wsel) & 0xffu) << 24);
    }
    *(uint4*)(dst + c * 16) = make_uint4(wo[0], wo[1], wo[2], wo[3]);
  }
}

// ------------- MFMA sliding-window attention (W=32) -------------
__global__ __launch_bounds__(256, 2) void attn_mfma(const __bf16* __restrict__ h,
                                                    const char* __restrict__ vTb,
                                                    char* __restrict__ fused8,
                                                    const float* __restrict__ pbm) {
  const int blk = blockIdx.x;          // 256
  const int qblk = blk & 7;
  const int head = (blk >> 3) & 3;
  const int b = blk >> 5;
  const int tid = threadIdx.x;
  const int lane = tid & 63;
  const int w = tid >> 6;
  __shared__ char vt[256 * 176];
  __shared__ char pl[4][32 * 80];

  const float p = pbm[0];
  const float sp = (p > 20.0f) ? p : log1pf(expf(p));

  {
    const int m = qblk * 2;
    const char* base = vTb + ((size_t)(b * 4 + head) * 16) * 16384;
    #pragma unroll
    for (int it = 0; it < 11; ++it) {
      const int U = it * 256 + tid;
      const int d = U / 11;
      const int slot = U - d * 11;
      int sb, so;
      if (slot >= 10)      { sb = m; so = 0; }
      else if (slot < 2)   { sb = m - 1; so = 32 + slot * 16; }
      else if (slot < 6)   { sb = m; so = (slot - 2) * 16; }
      else                 { sb = m + 1; so = (slot - 6) * 16; }
      if (sb < 0) sb = 0;
      async16(base + ((size_t)sb * 256 + d) * 64 + so, vt + U * 16);
    }
  }

  const int col = lane & 15;
  const int hi = lane >> 4;
  const int qb = qblk * 128 + w * 32;
  const int kb = qb - 32;

  f32x4 sc[4][2] = {};
  bf16x8 afr[4], bfr[2];
  #pragma unroll
  for (int mf = 0; mf < 4; ++mf) {
    int key = kb + mf * 16 + col;
    if (key < 0) key = 0;
    afr[mf] = *(const bf16x8*)&h[(size_t)(b * 1024 + key) * HQK + 128 + head * 32 + hi * 8];
  }
  #pragma unroll
  for (int nf = 0; nf < 2; ++nf)
    bfr[nf] = *(const bf16x8*)&h[(size_t)(b * 1024 + qb + nf * 16 + col) * HQK + head * 32 + hi * 8];
  #pragma unroll
  for (int mf = 0; mf < 4; ++mf)
    #pragma unroll
    for (int nf = 0; nf < 2; ++nf)
      sc[mf][nf] = __builtin_amdgcn_mfma_f32_16x16x32_bf16(afr[mf], bfr[nf], sc[mf][nf], 0, 0, 0);

  #pragma unroll
  for (int nf = 0; nf < 2; ++nf) {
    #pragma unroll
    for (int mf = 0; mf < 4; ++mf)
      #pragma unroll
      for (int r = 0; r < 4; ++r) {
        const int delta = mf * 16 + hi * 4 + r - nf * 16 - col - 32;
        const int keyabs = kb + mf * 16 + hi * 4 + r;
        const bool valid = (delta <= 0) & (delta >= -31) & (keyabs >= 0);
        sc[mf][nf][r] = valid ? sc[mf][nf][r] * 0.1767766953f + sp * (float)delta : -1e30f;
      }
    float m = -1e30f;
    #pragma unroll
    for (int mf = 0; mf < 4; ++mf)
      #pragma unroll
      for (int r = 0; r < 4; ++r) m = fmaxf(m, sc[mf][nf][r]);
    m = fmaxf(m, __shfl_xor(m, 16));
    m = fmaxf(m, __shfl_xor(m, 32));
    float s = 0.0f;
    #pragma unroll
    for (int mf = 0; mf < 4; ++mf)
      #pragma unroll
      for (int r = 0; r < 4; ++r) {
        const float e = __expf(sc[mf][nf][r] - m);
        sc[mf][nf][r] = e;
        s += e;
      }
    s += __shfl_xor(s, 16);
    s += __shfl_xor(s, 32);
    const float inv = 1.0f / s;
    #pragma unroll
    for (int mf = 0; mf < 4; ++mf) {
      const u32 pk = pack4_e4m3(sc[mf][nf][0] * inv, sc[mf][nf][1] * inv,
                                sc[mf][nf][2] * inv, sc[mf][nf][3] * inv);
      *(u32*)&pl[w][(nf * 16 + col) * 80 + mf * 16 + hi * 4] = pk;
    }
  }

  __syncthreads();

  const char* ppl = pl[w];
  const int kloc = w * 32;
  f32x4 ao[16][2] = {};
  #pragma unroll
  for (int kf = 0; kf < 2; ++kf) {
    long bfrag[2];
    #pragma unroll
    for (int nf = 0; nf < 2; ++nf)
      bfrag[nf] = *(const long*)&ppl[(nf * 16 + col) * 80 + kf * 32 + hi * 8];
    #pragma unroll
    for (int mf = 0; mf < 16; ++mf) {
      const long af = *(const long*)&vt[(mf * 16 + col) * 176 + kloc + kf * 32 + hi * 8];
      #pragma unroll
      for (int nf = 0; nf < 2; ++nf)
        ao[mf][nf] = __builtin_amdgcn_mfma_f32_16x16x32_fp8_fp8(af, bfrag[nf], ao[mf][nf], 0, 0, 0);
    }
  }

  #pragma unroll
  for (int mf = 0; mf < 16; ++mf)
    #pragma unroll
    for (int nf = 0; nf < 2; ++nf) {
      const u32 pk = pack4_e4m3(ao[mf][nf][0], ao[mf][nf][1], ao[mf][nf][2], ao[mf][nf][3]);
      *(u32*)&fused8[(size_t)(b * 1024 + qb + nf * 16 + col) * EDIM + 1024 +
                     head * 256 + mf * 16 + hi * 4] = pk;
    }
}

// ---------------- host launch ----------------
extern "C" void kernel_launch(void* const* d_in, const int* in_sizes, int n_in,
                              void* d_out, int out_size, void* d_ws, size_t ws_size,
                              hipStream_t stream) {
  const float* x = (const float*)d_in[0];
  const float* norm_w = (const float*)d_in[2];
  const float* expand_w = (const float*)d_in[3];
  const float* project_w = (const float*)d_in[4];
  const float* pbm = (const float*)d_in[5];
  float* out = (float*)d_out;

  char* ws = (char*)d_ws;
  __bf16* xn    = (__bf16*)(ws);                  // 16,777,216
  u32*    xn8   = (u32*)(ws + 16777216);          //  8,388,608
  __bf16* wqk   = (__bf16*)(ws + 25165824);       //    524,288
  char*   wexp8i= (char*)(ws + 25690112);         //  4,194,304 (interleaved, x16)
  char*   wproj8= (char*)(ws + 29884416);         //  2,097,152 (x256)
  __bf16* h     = (__bf16*)(ws + 31981568);       //  4,194,304 (q|k only)
  char*   fused8= (char*)(ws + 36175872);         // 16,777,216
  char*   vbuf8 = (char*)(ws + 52953088);         //  8,388,608
  char*   vTb   = (char*)(ws + 61341696);         //  8,388,608
  // total 69,730,304 bytes

  ln_kernel<<<MROWS, 256, 0, stream>>>(x, norm_w, xn, xn8);
  cast_kernel<<<256, 256, 0, stream>>>(expand_w, wqk, 65536);
  cast8i_kernel<<<4096, 256, 0, stream>>>(expand_w + 256 * DDIM, (u32*)wexp8i);
  cast8_kernel<<<2048, 256, 0, stream>>>(project_w, (u32*)wproj8, 524288, 256.0f);
  // q/k columns: M=8192, N=256, K=1024 (bf16)
  gemm_bt<<<dim3(64, 2), 256, 0, stream>>>(xn, wqk, h, HQK, DDIM, 0);
  // expand + fused GEGLU: 64 m x 16 n = 1024 blocks
  gemm1glu<<<1024, 512, 0, stream>>>((const char*)xn8, wexp8i, fused8, vbuf8);
  vT8_kernel<<<512, 256, 0, stream>>>(vbuf8, vTb);
  attn_mfma<<<256, 256, 0, stream>>>(h, vTb, fused8, pbm);
  // project: M=8192 (128 tiles) x N=1024 (4 tiles) = 512 blocks, BK=128
  gemmproj<<<512, 512, 0, stream>>>(fused8, wproj8, out, x, 1.0f / 256.0f);
}